// Round 6
// baseline (236.562 us; speedup 1.0000x reference)
//
#include <hip/hip_runtime.h>
#include <math.h>

typedef short bf16x8 __attribute__((ext_vector_type(8)));
typedef float f32x4  __attribute__((ext_vector_type(4)));

#define NPOS 32768

// ---- workspace byte offsets ----
#define OFF_CHI   0u            // short [32768][1024]  67108864
#define OFF_AHI   100663296u    // short [32768][256]   16777216
#define OFF_ATTN  134217728u    // short [32768][256]   16777216
#define OFF_BIAST 150994944u    // float [8][256][256]   2097152  (layout [h][i][j])
#define OFF_WHI   153354240u    // short [1024][256]      524288
#define OFF_W2P   154402816u    // short [256][256]       131072
#define OFF_GBP   154533888u    // float [256]              1024

__device__ __forceinline__ short f2bf(float x) {
    unsigned int u = __float_as_uint(x);
    unsigned int r = (u + 0x7FFFu + ((u >> 16) & 1u)) >> 16;
    return (short)r;
}
__device__ __forceinline__ float bf2f(short s) {
    return __uint_as_float(((unsigned int)(unsigned short)s) << 16);
}
__device__ __forceinline__ void async_copy16(const void* g, void* l) {
    __builtin_amdgcn_global_load_lds(
        (const __attribute__((address_space(1))) unsigned int*)g,
        (__attribute__((address_space(3))) unsigned int*)l, 16, 0, 0);
}

// ---------------- kernel 1: merged prologue ----------------
// blocks [0,8192): layernorm + bf16 cast of x1d
// blocks [8192,9473): weight permute + cast
// blocks [9473,10497): pair bias -> biasH[h][i][j]
__global__ __launch_bounds__(256) void k_prologue(
    const float* __restrict__ x, const float* __restrict__ nw, const float* __restrict__ nbias,
    const float* __restrict__ qkvw, const float* __restrict__ gatew,
    const float* __restrict__ gateb, const float* __restrict__ finalw,
    const float* __restrict__ x2d, const float* __restrict__ x2dw,
    short* __restrict__ Ahi, short* __restrict__ Whi, short* __restrict__ W2p,
    float* __restrict__ gbp, float* __restrict__ biasH) {
    const int b = blockIdx.x, t = threadIdx.x;
    if (b < 8192) {
        // ---- layernorm + cast ----
        int wid = (b * 256 + t) >> 6;
        int lane = t & 63;
        const float4 v = ((const float4*)(x + (size_t)wid * 256))[lane];
        float s  = v.x + v.y + v.z + v.w;
        float ss = v.x*v.x + v.y*v.y + v.z*v.z + v.w*v.w;
        #pragma unroll
        for (int o = 32; o; o >>= 1) {
            s  += __shfl_xor(s,  o, 64);
            ss += __shfl_xor(ss, o, 64);
        }
        float mu  = s * (1.0f / 256);
        float var = ss * (1.0f / 256) - mu * mu;
        float rs  = rsqrtf(var + 1e-5f);
        const float4 wv = ((const float4*)nw)[lane];
        const float4 bv = ((const float4*)nbias)[lane];
        float y[4] = {(v.x - mu) * rs * wv.x + bv.x, (v.y - mu) * rs * wv.y + bv.y,
                      (v.z - mu) * rs * wv.z + bv.z, (v.w - mu) * rs * wv.w + bv.w};
        short h4[4];
        #pragma unroll
        for (int i = 0; i < 4; ++i) h4[i] = f2bf(y[i]);
        *(short4*)(Ahi + (size_t)wid * 256 + lane * 4) = *(short4*)h4;
    } else if (b < 9473) {
        // ---- weight permute + cast ----
        int r = b - 8192;
        if (r < 1024) {
            int which = r >> 8, h = (r >> 5) & 7, c = r & 31;
            const float* src = (which < 3) ? qkvw + (size_t)(c * 24 + which * 8 + h) * 256
                                           : gatew + (size_t)(c * 8 + h) * 256;
            Whi[(size_t)r * 256 + t] = f2bf(src[t]);
        } else if (r < 1280) {
            int o = r - 1024;
            int h = t >> 5, c = t & 31;
            W2p[(size_t)o * 256 + t] = f2bf(finalw[(size_t)o * 256 + c * 8 + h]);
        } else {
            int h = t >> 5, c = t & 31;
            gbp[t] = gateb[c * 8 + h];
        }
    } else {
        // ---- pair bias: 64 rows (fixed i, consecutive j) per block ----
        __shared__ float xs[64][132];
        __shared__ float ws[8][132];
        const int wid0 = (b - 9473) * 64;          // global row = i*256 + j
        #pragma unroll
        for (int r = 0; r < 8; ++r) {
            int g = r * 256 + t;
            int row = g >> 5, c4 = g & 31;
            float4 v = *(const float4*)(x2d + (size_t)(wid0 + row) * 128 + c4 * 4);
            *(float4*)&xs[row][c4 * 4] = v;
        }
        {
            int h = t >> 5, c4 = t & 31;
            *(float4*)&ws[h][c4 * 4] = *(const float4*)(x2dw + h * 128 + c4 * 4);
        }
        __syncthreads();
        const float f = 0.17677669529663687f;      // 1/sqrt(32)
        const int i = wid0 >> 8;
        #pragma unroll
        for (int kk = 0; kk < 2; ++kk) {
            int o = t + kk * 256;
            int row = o >> 3, h = o & 7;
            float acc = 0.f;
            #pragma unroll
            for (int c4 = 0; c4 < 32; ++c4) {
                float4 xv = *(const float4*)&xs[row][c4 * 4];
                float4 wv = *(const float4*)&ws[h][c4 * 4];
                acc += xv.x * wv.x + xv.y * wv.y + xv.z * wv.z + xv.w * wv.w;
            }
            int j = (wid0 & 255) + row;
            biasH[(((h * 256 + i)) << 8) + j] = acc * f;   // [h][i][j]
        }
    }
}

// ---------------- kernel 2: MFMA GEMM1, single pass bf16 ----------------
__global__ __launch_bounds__(256) void k_gemm1m(
    const short* __restrict__ Ahi, const short* __restrict__ Whi,
    const float* __restrict__ gbp, short* __restrict__ Chi) {
    __shared__ short As[128 * 64];
    __shared__ short Bs[128 * 64];
    const int t = threadIdx.x;
    const int wave = t >> 6, lane = t & 63, ln15 = lane & 15, quad = lane >> 4;
    const int posBase = blockIdx.x * 128;
    const int nb = blockIdx.y;
    const int i0w = (wave & 1) * 64, n0w = (wave >> 1) * 64;

    f32x4 acc[4][4];
    #pragma unroll
    for (int a = 0; a < 4; ++a)
        #pragma unroll
        for (int b = 0; b < 4; ++b) acc[a][b] = (f32x4){0.f, 0.f, 0.f, 0.f};

    for (int k0 = 0; k0 < 256; k0 += 64) {
        #pragma unroll
        for (int r = 0; r < 4; ++r) {
            int g = r * 256 + t;
            int row = g >> 3, cs = g & 7;
            int colg = cs ^ (row & 7);                 // XOR swizzle
            size_t aoff = (size_t)(posBase + row) * 256 + k0 + colg * 8;
            size_t boff = (size_t)(nb * 128 + row) * 256 + k0 + colg * 8;
            int ldst = (r * 256 + wave * 64) * 8;
            async_copy16(Ahi + aoff, &As[ldst]);
            async_copy16(Whi + boff, &Bs[ldst]);
        }
        __syncthreads();
        #pragma unroll
        for (int kc = 0; kc < 2; ++kc) {
            bf16x8 af[4], bfr[4];
            #pragma unroll
            for (int it = 0; it < 4; ++it) {
                int rowa = i0w + it * 16 + ln15;
                int c8a = (kc * 4 + quad) ^ (rowa & 7);
                af[it] = *(const bf16x8*)&As[rowa * 64 + c8a * 8];
                int rowb = n0w + it * 16 + ln15;
                int c8b = (kc * 4 + quad) ^ (rowb & 7);
                bfr[it] = *(const bf16x8*)&Bs[rowb * 64 + c8b * 8];
            }
            #pragma unroll
            for (int it = 0; it < 4; ++it)
                #pragma unroll
                for (int nt = 0; nt < 4; ++nt)
                    acc[it][nt] = __builtin_amdgcn_mfma_f32_16x16x32_bf16(
                        af[it], bfr[nt], acc[it][nt], 0, 0, 0);
        }
        __syncthreads();
    }
    const bool isgate = (nb >= 6);
    #pragma unroll
    for (int it = 0; it < 4; ++it)
        #pragma unroll
        for (int nt = 0; nt < 4; ++nt)
            #pragma unroll
            for (int r = 0; r < 4; ++r) {
                size_t pos = posBase + i0w + it * 16 + quad * 4 + r;
                int ncol = nb * 128 + n0w + nt * 16 + ln15;
                float val = acc[it][nt][r];
                if (isgate) val = 1.0f / (1.0f + __expf(-(val + gbp[ncol - 768])));
                Chi[pos * 1024 + ncol] = f2bf(val);
            }
}

// ---------------- kernel 3: MFMA attention, no-max softmax ----------------
__global__ __launch_bounds__(512) void k_attn3(
    const short* __restrict__ Chi, const float* __restrict__ biasH,
    short* __restrict__ attnB) {
    __shared__ short Khi[256 * 32];        // [j][chunk], source-swizzled
    __shared__ short VT[32 * 264];         // [c][j], padded
    __shared__ short Pl[8][16][40];

    const int mh = blockIdx.x;
    const int m = mh >> 3, h = mh & 7;
    const int t = threadIdx.x;
    const int wave = t >> 6, lane = t & 63, ln15 = lane & 15, quad = lane >> 4;
    const int i0 = wave * 32;

    #pragma unroll
    for (int r = 0; r < 2; ++r) {
        int g = r * 512 + t;
        int j = g >> 2, c16 = g & 3;
        int cs = c16 ^ (j & 3);
        const short* gp = Chi + (size_t)(m * 256 + j) * 1024 + 256 + h * 32 + cs * 8;
        async_copy16(gp, &Khi[(r * 512 + wave * 64) * 8]);
    }
    {
        int j = t & 255, c0 = (t >> 8) * 16;
        const short* vp = Chi + (size_t)(m * 256 + j) * 1024 + 512 + h * 32 + c0;
        bf16x8 v0 = *(const bf16x8*)vp;
        bf16x8 v1 = *(const bf16x8*)(vp + 8);
        #pragma unroll
        for (int c = 0; c < 8; ++c) VT[(c0 + c) * 264 + j] = v0[c];
        #pragma unroll
        for (int c = 0; c < 8; ++c) VT[(c0 + 8 + c) * 264 + j] = v1[c];
    }
    bf16x8 qhi[2];
    #pragma unroll
    for (int it = 0; it < 2; ++it) {
        int i = i0 + it * 16 + ln15;
        qhi[it] = *(const bf16x8*)(Chi + (size_t)(m * 256 + i) * 1024 + h * 32 + quad * 8);
    }
    __syncthreads();

    float lacc[2] = {0.f, 0.f};
    f32x4 Oacc[2][2];
    #pragma unroll
    for (int a = 0; a < 2; ++a) {
        Oacc[a][0] = (f32x4){0.f, 0.f, 0.f, 0.f};
        Oacc[a][1] = (f32x4){0.f, 0.f, 0.f, 0.f};
    }
    const float* bp = biasH + (size_t)h * 65536;   // [i][j], j contiguous

    for (int j0 = 0; j0 < 256; j0 += 32) {
        bf16x8 kfh[2], vf[2];
        #pragma unroll
        for (int jt = 0; jt < 2; ++jt) {
            int j = j0 + jt * 16 + ln15;
            int cs = quad ^ (j & 3);
            kfh[jt] = *(const bf16x8*)&Khi[j * 32 + cs * 8];
        }
        #pragma unroll
        for (int ct = 0; ct < 2; ++ct) {
            int c = ct * 16 + ln15;
            vf[ct] = *(const bf16x8*)&VT[c * 264 + j0 + quad * 8];
        }
        #pragma unroll
        for (int it = 0; it < 2; ++it) {
            int i = i0 + it * 16 + ln15;
            // vector bias loads: S D-layout has j in regs -> float4 over j
            float b0a[4], b1a[4];
            *(float4*)b0a = *(const float4*)(bp + (size_t)i * 256 + j0 + quad * 4);
            *(float4*)b1a = *(const float4*)(bp + (size_t)i * 256 + j0 + 16 + quad * 4);
            f32x4 s0 = (f32x4){0.f, 0.f, 0.f, 0.f};
            f32x4 s1 = (f32x4){0.f, 0.f, 0.f, 0.f};
            s0 = __builtin_amdgcn_mfma_f32_16x16x32_bf16(kfh[0], qhi[it], s0, 0, 0, 0);
            s1 = __builtin_amdgcn_mfma_f32_16x16x32_bf16(kfh[1], qhi[it], s1, 0, 0, 0);
            // unnormalized softmax: scores bounded (|s|max ~ 35 << 88)
            float p[8], ps = 0.f;
            #pragma unroll
            for (int r = 0; r < 4; ++r) { p[r] = __expf(s0[r] + b0a[r]); ps += p[r]; }
            #pragma unroll
            for (int r = 0; r < 4; ++r) { p[4 + r] = __expf(s1[r] + b1a[r]); ps += p[4 + r]; }
            lacc[it] += ps;
            unsigned long long pw0 =
                  (unsigned long long)(unsigned short)f2bf(p[0])
                | ((unsigned long long)(unsigned short)f2bf(p[1]) << 16)
                | ((unsigned long long)(unsigned short)f2bf(p[2]) << 32)
                | ((unsigned long long)(unsigned short)f2bf(p[3]) << 48);
            unsigned long long pw1 =
                  (unsigned long long)(unsigned short)f2bf(p[4])
                | ((unsigned long long)(unsigned short)f2bf(p[5]) << 16)
                | ((unsigned long long)(unsigned short)f2bf(p[6]) << 32)
                | ((unsigned long long)(unsigned short)f2bf(p[7]) << 48);
            *(unsigned long long*)&Pl[wave][ln15][quad * 4]      = pw0;
            *(unsigned long long*)&Pl[wave][ln15][16 + quad * 4] = pw1;
            bf16x8 pf = *(const bf16x8*)&Pl[wave][ln15][quad * 8];
            Oacc[it][0] = __builtin_amdgcn_mfma_f32_16x16x32_bf16(pf, vf[0], Oacc[it][0], 0, 0, 0);
            Oacc[it][1] = __builtin_amdgcn_mfma_f32_16x16x32_bf16(pf, vf[1], Oacc[it][1], 0, 0, 0);
        }
    }
    #pragma unroll
    for (int it = 0; it < 2; ++it) {
        float l = lacc[it];
        l += __shfl_xor(l, 16, 64);
        l += __shfl_xor(l, 32, 64);
        float inv = 1.0f / l;
        float invr[4];
        #pragma unroll
        for (int r = 0; r < 4; ++r) invr[r] = __shfl(inv, quad * 4 + r, 16);
        #pragma unroll
        for (int ct = 0; ct < 2; ++ct) {
            int c = ct * 16 + ln15;
            #pragma unroll
            for (int r = 0; r < 4; ++r) {
                int i = i0 + it * 16 + quad * 4 + r;
                float g = bf2f(Chi[(size_t)(m * 256 + i) * 1024 + 768 + h * 32 + c]);
                float val = Oacc[it][ct][r] * invr[r] * g;
                attnB[(size_t)(m * 256 + i) * 256 + h * 32 + c] = f2bf(val);
            }
        }
    }
}

// ---------------- kernel 4: MFMA GEMM2  out[32768][256] ----------------
__global__ __launch_bounds__(256) void k_gemm2m(
    const short* __restrict__ A, const short* __restrict__ W2p,
    const float* __restrict__ fb, float* __restrict__ out) {
    __shared__ short As[128 * 64];
    __shared__ short Bs[128 * 64];
    const int t = threadIdx.x;
    const int wave = t >> 6, lane = t & 63, ln15 = lane & 15, quad = lane >> 4;
    const int posBase = blockIdx.x * 128;
    const int nb = blockIdx.y;
    const int i0w = (wave & 1) * 64, n0w = (wave >> 1) * 64;

    f32x4 acc[4][4];
    #pragma unroll
    for (int a = 0; a < 4; ++a)
        #pragma unroll
        for (int b = 0; b < 4; ++b) acc[a][b] = (f32x4){0.f, 0.f, 0.f, 0.f};

    for (int k0 = 0; k0 < 256; k0 += 64) {
        #pragma unroll
        for (int r = 0; r < 4; ++r) {
            int g = r * 256 + t;
            int row = g >> 3, cs = g & 7;
            int colg = cs ^ (row & 7);
            const short* ga = A + (size_t)(posBase + row) * 256 + k0 + colg * 8;
            async_copy16(ga, &As[(r * 256 + wave * 64) * 8]);
            const short* gb = W2p + (size_t)(nb * 128 + row) * 256 + k0 + colg * 8;
            async_copy16(gb, &Bs[(r * 256 + wave * 64) * 8]);
        }
        __syncthreads();
        #pragma unroll
        for (int kc = 0; kc < 2; ++kc) {
            bf16x8 af[4], bfr[4];
            #pragma unroll
            for (int it = 0; it < 4; ++it) {
                int rowa = i0w + it * 16 + ln15;
                int c8a = (kc * 4 + quad) ^ (rowa & 7);
                af[it] = *(const bf16x8*)&As[rowa * 64 + c8a * 8];
                int rowb = n0w + it * 16 + ln15;
                int c8b = (kc * 4 + quad) ^ (rowb & 7);
                bfr[it] = *(const bf16x8*)&Bs[rowb * 64 + c8b * 8];
            }
            #pragma unroll
            for (int it = 0; it < 4; ++it)
                #pragma unroll
                for (int nt = 0; nt < 4; ++nt)
                    acc[it][nt] = __builtin_amdgcn_mfma_f32_16x16x32_bf16(
                        af[it], bfr[nt], acc[it][nt], 0, 0, 0);
        }
        __syncthreads();
    }
    #pragma unroll
    for (int it = 0; it < 4; ++it)
        #pragma unroll
        for (int nt = 0; nt < 4; ++nt)
            #pragma unroll
            for (int r = 0; r < 4; ++r) {
                size_t pos = posBase + i0w + it * 16 + quad * 4 + r;
                int ncol = nb * 128 + n0w + nt * 16 + ln15;
                out[pos * 256 + ncol] = acc[it][nt][r] + fb[ncol];
            }
}

extern "C" void kernel_launch(void* const* d_in, const int* in_sizes, int n_in,
                              void* d_out, int out_size, void* d_ws, size_t ws_size,
                              hipStream_t stream) {
    const float* x1d     = (const float*)d_in[0];
    const float* x2d     = (const float*)d_in[1];
    const float* norm_w  = (const float*)d_in[2];
    const float* norm_b  = (const float*)d_in[3];
    const float* qkv_w   = (const float*)d_in[4];
    const float* x2d_w   = (const float*)d_in[5];
    const float* gate_w  = (const float*)d_in[6];
    const float* gate_b  = (const float*)d_in[7];
    const float* final_w = (const float*)d_in[8];
    const float* final_b = (const float*)d_in[9];
    float* out = (float*)d_out;
    char* w = (char*)d_ws;

    short* Chi   = (short*)(w + OFF_CHI);
    short* Ahi   = (short*)(w + OFF_AHI);
    short* attnB = (short*)(w + OFF_ATTN);
    float* biasH = (float*)(w + OFF_BIAST);
    short* Whi   = (short*)(w + OFF_WHI);
    short* W2p   = (short*)(w + OFF_W2P);
    float* gbp   = (float*)(w + OFF_GBP);

    k_prologue<<<10497, 256, 0, stream>>>(x1d, norm_w, norm_b, qkv_w, gate_w, gate_b,
                                          final_w, x2d, x2d_w, Ahi, Whi, W2p, gbp, biasH);
    k_gemm1m<<<dim3(256, 8), 256, 0, stream>>>(Ahi, Whi, gbp, Chi);
    k_attn3<<<1024, 512, 0, stream>>>(Chi, biasH, attnB);
    k_gemm2m<<<dim3(256, 2), 256, 0, stream>>>(attnB, W2p, final_b, out);
}

// Round 7
// 226.172 us; speedup vs baseline: 1.0459x; 1.0459x over previous
//
#include <hip/hip_runtime.h>
#include <math.h>

typedef short bf16x8 __attribute__((ext_vector_type(8)));
typedef float f32x4  __attribute__((ext_vector_type(4)));

#define NPOS 32768

// ---- workspace byte offsets ----
#define OFF_CHI   0u            // short [32768][1024]  67108864
#define OFF_AHI   100663296u    // short [32768][256]   16777216
#define OFF_ATTN  134217728u    // short [32768][256]   16777216
#define OFF_BIAST 150994944u    // float [8][256][256]   2097152  (layout [h][j][i])
#define OFF_WHI   153354240u    // short [1024][256]      524288
#define OFF_W2P   154402816u    // short [256][256]       131072
#define OFF_GBP   154533888u    // float [256]              1024

__device__ __forceinline__ short f2bf(float x) {
    unsigned int u = __float_as_uint(x);
    unsigned int r = (u + 0x7FFFu + ((u >> 16) & 1u)) >> 16;
    return (short)r;
}
__device__ __forceinline__ float bf2f(short s) {
    return __uint_as_float(((unsigned int)(unsigned short)s) << 16);
}
__device__ __forceinline__ void async_copy16(const void* g, void* l) {
    __builtin_amdgcn_global_load_lds(
        (const __attribute__((address_space(1))) unsigned int*)g,
        (__attribute__((address_space(3))) unsigned int*)l, 16, 0, 0);
}

// ---------------- kernel 1: merged prologue ----------------
// blocks [0,8192): layernorm + bf16 cast of x1d
// blocks [8192,9473): weight permute + cast
// blocks [9473,10497): pair bias -> biasT[h][j][i]
__global__ __launch_bounds__(256) void k_prologue(
    const float* __restrict__ x, const float* __restrict__ nw, const float* __restrict__ nbias,
    const float* __restrict__ qkvw, const float* __restrict__ gatew,
    const float* __restrict__ gateb, const float* __restrict__ finalw,
    const float* __restrict__ x2d, const float* __restrict__ x2dw,
    short* __restrict__ Ahi, short* __restrict__ Whi, short* __restrict__ W2p,
    float* __restrict__ gbp, float* __restrict__ biasT) {
    const int b = blockIdx.x, t = threadIdx.x;
    if (b < 8192) {
        // ---- layernorm + cast ----
        int wid = (b * 256 + t) >> 6;
        int lane = t & 63;
        const float4 v = ((const float4*)(x + (size_t)wid * 256))[lane];
        float s  = v.x + v.y + v.z + v.w;
        float ss = v.x*v.x + v.y*v.y + v.z*v.z + v.w*v.w;
        #pragma unroll
        for (int o = 32; o; o >>= 1) {
            s  += __shfl_xor(s,  o, 64);
            ss += __shfl_xor(ss, o, 64);
        }
        float mu  = s * (1.0f / 256);
        float var = ss * (1.0f / 256) - mu * mu;
        float rs  = rsqrtf(var + 1e-5f);
        const float4 wv = ((const float4*)nw)[lane];
        const float4 bv = ((const float4*)nbias)[lane];
        float y[4] = {(v.x - mu) * rs * wv.x + bv.x, (v.y - mu) * rs * wv.y + bv.y,
                      (v.z - mu) * rs * wv.z + bv.z, (v.w - mu) * rs * wv.w + bv.w};
        short h4[4];
        #pragma unroll
        for (int i = 0; i < 4; ++i) h4[i] = f2bf(y[i]);
        *(short4*)(Ahi + (size_t)wid * 256 + lane * 4) = *(short4*)h4;
    } else if (b < 9473) {
        // ---- weight permute + cast ----
        int r = b - 8192;
        if (r < 1024) {
            int which = r >> 8, h = (r >> 5) & 7, c = r & 31;
            const float* src = (which < 3) ? qkvw + (size_t)(c * 24 + which * 8 + h) * 256
                                           : gatew + (size_t)(c * 8 + h) * 256;
            Whi[(size_t)r * 256 + t] = f2bf(src[t]);
        } else if (r < 1280) {
            int o = r - 1024;
            int h = t >> 5, c = t & 31;
            W2p[(size_t)o * 256 + t] = f2bf(finalw[(size_t)o * 256 + c * 8 + h]);
        } else {
            int h = t >> 5, c = t & 31;
            gbp[t] = gateb[c * 8 + h];
        }
    } else {
        // ---- pair bias: 64 rows (fixed i, consecutive j) per block ----
        __shared__ float xs[64][132];
        __shared__ float ws[8][132];
        const int wid0 = (b - 9473) * 64;          // global row = i*256 + j
        #pragma unroll
        for (int r = 0; r < 8; ++r) {
            int g = r * 256 + t;
            int row = g >> 5, c4 = g & 31;
            float4 v = *(const float4*)(x2d + (size_t)(wid0 + row) * 128 + c4 * 4);
            *(float4*)&xs[row][c4 * 4] = v;
        }
        {
            int h = t >> 5, c4 = t & 31;
            *(float4*)&ws[h][c4 * 4] = *(const float4*)(x2dw + h * 128 + c4 * 4);
        }
        __syncthreads();
        const float f = 0.17677669529663687f;      // 1/sqrt(32)
        const int i = wid0 >> 8;
        #pragma unroll
        for (int kk = 0; kk < 2; ++kk) {
            int o = t + kk * 256;
            int row = o >> 3, h = o & 7;
            float acc = 0.f;
            #pragma unroll
            for (int c4 = 0; c4 < 32; ++c4) {
                float4 xv = *(const float4*)&xs[row][c4 * 4];
                float4 wv = *(const float4*)&ws[h][c4 * 4];
                acc += xv.x * wv.x + xv.y * wv.y + xv.z * wv.z + xv.w * wv.w;
            }
            int j = (wid0 & 255) + row;
            biasT[(((h * 256 + j)) << 8) + i] = acc * f;   // [h][j][i]
        }
    }
}

// ---------------- kernel 2: MFMA GEMM1, single pass bf16 ----------------
__global__ __launch_bounds__(256) void k_gemm1m(
    const short* __restrict__ Ahi, const short* __restrict__ Whi,
    const float* __restrict__ gbp, short* __restrict__ Chi) {
    __shared__ short As[128 * 64];
    __shared__ short Bs[128 * 64];
    const int t = threadIdx.x;
    const int wave = t >> 6, lane = t & 63, ln15 = lane & 15, quad = lane >> 4;
    const int posBase = blockIdx.x * 128;
    const int nb = blockIdx.y;
    const int i0w = (wave & 1) * 64, n0w = (wave >> 1) * 64;

    f32x4 acc[4][4];
    #pragma unroll
    for (int a = 0; a < 4; ++a)
        #pragma unroll
        for (int b = 0; b < 4; ++b) acc[a][b] = (f32x4){0.f, 0.f, 0.f, 0.f};

    for (int k0 = 0; k0 < 256; k0 += 64) {
        #pragma unroll
        for (int r = 0; r < 4; ++r) {
            int g = r * 256 + t;
            int row = g >> 3, cs = g & 7;
            int colg = cs ^ (row & 7);                 // XOR swizzle
            size_t aoff = (size_t)(posBase + row) * 256 + k0 + colg * 8;
            size_t boff = (size_t)(nb * 128 + row) * 256 + k0 + colg * 8;
            int ldst = (r * 256 + wave * 64) * 8;
            async_copy16(Ahi + aoff, &As[ldst]);
            async_copy16(Whi + boff, &Bs[ldst]);
        }
        __syncthreads();
        #pragma unroll
        for (int kc = 0; kc < 2; ++kc) {
            bf16x8 af[4], bfr[4];
            #pragma unroll
            for (int it = 0; it < 4; ++it) {
                int rowa = i0w + it * 16 + ln15;
                int c8a = (kc * 4 + quad) ^ (rowa & 7);
                af[it] = *(const bf16x8*)&As[rowa * 64 + c8a * 8];
                int rowb = n0w + it * 16 + ln15;
                int c8b = (kc * 4 + quad) ^ (rowb & 7);
                bfr[it] = *(const bf16x8*)&Bs[rowb * 64 + c8b * 8];
            }
            #pragma unroll
            for (int it = 0; it < 4; ++it)
                #pragma unroll
                for (int nt = 0; nt < 4; ++nt)
                    acc[it][nt] = __builtin_amdgcn_mfma_f32_16x16x32_bf16(
                        af[it], bfr[nt], acc[it][nt], 0, 0, 0);
        }
        __syncthreads();
    }
    const bool isgate = (nb >= 6);
    #pragma unroll
    for (int it = 0; it < 4; ++it)
        #pragma unroll
        for (int nt = 0; nt < 4; ++nt)
            #pragma unroll
            for (int r = 0; r < 4; ++r) {
                size_t pos = posBase + i0w + it * 16 + quad * 4 + r;
                int ncol = nb * 128 + n0w + nt * 16 + ln15;
                float val = acc[it][nt][r];
                if (isgate) val = 1.0f / (1.0f + __expf(-(val + gbp[ncol - 768])));
                Chi[pos * 1024 + ncol] = f2bf(val);
            }
}

// ---------------- kernel 3: MFMA attention, no-max softmax, unrolled j0 ----------------
__global__ __launch_bounds__(512) void k_attn3(
    const short* __restrict__ Chi, const float* __restrict__ biasT,
    short* __restrict__ attnB) {
    __shared__ short Khi[256 * 32];        // [j][chunk], source-swizzled
    __shared__ short VT[32 * 264];         // [c][j], padded
    __shared__ short Pl[8][16][40];

    const int mh = blockIdx.x;
    const int m = mh >> 3, h = mh & 7;
    const int t = threadIdx.x;
    const int wave = t >> 6, lane = t & 63, ln15 = lane & 15, quad = lane >> 4;
    const int i0 = wave * 32;

    #pragma unroll
    for (int r = 0; r < 2; ++r) {
        int g = r * 512 + t;
        int j = g >> 2, c16 = g & 3;
        int cs = c16 ^ (j & 3);
        const short* gp = Chi + (size_t)(m * 256 + j) * 1024 + 256 + h * 32 + cs * 8;
        async_copy16(gp, &Khi[(r * 512 + wave * 64) * 8]);
    }
    {
        int j = t & 255, c0 = (t >> 8) * 16;
        const short* vp = Chi + (size_t)(m * 256 + j) * 1024 + 512 + h * 32 + c0;
        bf16x8 v0 = *(const bf16x8*)vp;
        bf16x8 v1 = *(const bf16x8*)(vp + 8);
        #pragma unroll
        for (int c = 0; c < 8; ++c) VT[(c0 + c) * 264 + j] = v0[c];
        #pragma unroll
        for (int c = 0; c < 8; ++c) VT[(c0 + 8 + c) * 264 + j] = v1[c];
    }
    bf16x8 qhi[2];
    #pragma unroll
    for (int it = 0; it < 2; ++it) {
        int i = i0 + it * 16 + ln15;
        qhi[it] = *(const bf16x8*)(Chi + (size_t)(m * 256 + i) * 1024 + h * 32 + quad * 8);
    }
    __syncthreads();

    float lacc[2] = {0.f, 0.f};
    f32x4 Oacc[2][2];
    #pragma unroll
    for (int a = 0; a < 2; ++a) {
        Oacc[a][0] = (f32x4){0.f, 0.f, 0.f, 0.f};
        Oacc[a][1] = (f32x4){0.f, 0.f, 0.f, 0.f};
    }
    const float* bp = biasT + (size_t)h * 65536;   // [j][i], i contiguous

    #pragma unroll
    for (int j0 = 0; j0 < 256; j0 += 32) {
        bf16x8 kfh[2], vf[2];
        #pragma unroll
        for (int jt = 0; jt < 2; ++jt) {
            int j = j0 + jt * 16 + ln15;
            int cs = quad ^ (j & 3);
            kfh[jt] = *(const bf16x8*)&Khi[j * 32 + cs * 8];
        }
        #pragma unroll
        for (int ct = 0; ct < 2; ++ct) {
            int c = ct * 16 + ln15;
            vf[ct] = *(const bf16x8*)&VT[c * 264 + j0 + quad * 8];
        }
        #pragma unroll
        for (int it = 0; it < 2; ++it) {
            int i = i0 + it * 16 + ln15;
            float b0a[4], b1a[4];
            #pragma unroll
            for (int r = 0; r < 4; ++r) {
                b0a[r] = bp[(j0 + quad * 4 + r) * 256 + i];
                b1a[r] = bp[(j0 + 16 + quad * 4 + r) * 256 + i];
            }
            f32x4 s0 = (f32x4){0.f, 0.f, 0.f, 0.f};
            f32x4 s1 = (f32x4){0.f, 0.f, 0.f, 0.f};
            s0 = __builtin_amdgcn_mfma_f32_16x16x32_bf16(kfh[0], qhi[it], s0, 0, 0, 0);
            s1 = __builtin_amdgcn_mfma_f32_16x16x32_bf16(kfh[1], qhi[it], s1, 0, 0, 0);
            // unnormalized softmax: scores bounded (|s|max ~ 35 << 88)
            float p[8], ps = 0.f;
            #pragma unroll
            for (int r = 0; r < 4; ++r) { p[r] = __expf(s0[r] + b0a[r]); ps += p[r]; }
            #pragma unroll
            for (int r = 0; r < 4; ++r) { p[4 + r] = __expf(s1[r] + b1a[r]); ps += p[4 + r]; }
            lacc[it] += ps;
            unsigned long long pw0 =
                  (unsigned long long)(unsigned short)f2bf(p[0])
                | ((unsigned long long)(unsigned short)f2bf(p[1]) << 16)
                | ((unsigned long long)(unsigned short)f2bf(p[2]) << 32)
                | ((unsigned long long)(unsigned short)f2bf(p[3]) << 48);
            unsigned long long pw1 =
                  (unsigned long long)(unsigned short)f2bf(p[4])
                | ((unsigned long long)(unsigned short)f2bf(p[5]) << 16)
                | ((unsigned long long)(unsigned short)f2bf(p[6]) << 32)
                | ((unsigned long long)(unsigned short)f2bf(p[7]) << 48);
            *(unsigned long long*)&Pl[wave][ln15][quad * 4]      = pw0;
            *(unsigned long long*)&Pl[wave][ln15][16 + quad * 4] = pw1;
            bf16x8 pf = *(const bf16x8*)&Pl[wave][ln15][quad * 8];
            Oacc[it][0] = __builtin_amdgcn_mfma_f32_16x16x32_bf16(pf, vf[0], Oacc[it][0], 0, 0, 0);
            Oacc[it][1] = __builtin_amdgcn_mfma_f32_16x16x32_bf16(pf, vf[1], Oacc[it][1], 0, 0, 0);
        }
    }
    #pragma unroll
    for (int it = 0; it < 2; ++it) {
        float l = lacc[it];
        l += __shfl_xor(l, 16, 64);
        l += __shfl_xor(l, 32, 64);
        float inv = 1.0f / l;
        float invr[4];
        #pragma unroll
        for (int r = 0; r < 4; ++r) invr[r] = __shfl(inv, quad * 4 + r, 16);
        #pragma unroll
        for (int ct = 0; ct < 2; ++ct) {
            int c = ct * 16 + ln15;
            #pragma unroll
            for (int r = 0; r < 4; ++r) {
                int i = i0 + it * 16 + quad * 4 + r;
                float g = bf2f(Chi[(size_t)(m * 256 + i) * 1024 + 768 + h * 32 + c]);
                float val = Oacc[it][ct][r] * invr[r] * g;
                attnB[(size_t)(m * 256 + i) * 256 + h * 32 + c] = f2bf(val);
            }
        }
    }
}

// ---------------- kernel 4: MFMA GEMM2  out[32768][256] ----------------
__global__ __launch_bounds__(256) void k_gemm2m(
    const short* __restrict__ A, const short* __restrict__ W2p,
    const float* __restrict__ fb, float* __restrict__ out) {
    __shared__ short As[128 * 64];
    __shared__ short Bs[128 * 64];
    const int t = threadIdx.x;
    const int wave = t >> 6, lane = t & 63, ln15 = lane & 15, quad = lane >> 4;
    const int posBase = blockIdx.x * 128;
    const int nb = blockIdx.y;
    const int i0w = (wave & 1) * 64, n0w = (wave >> 1) * 64;

    f32x4 acc[4][4];
    #pragma unroll
    for (int a = 0; a < 4; ++a)
        #pragma unroll
        for (int b = 0; b < 4; ++b) acc[a][b] = (f32x4){0.f, 0.f, 0.f, 0.f};

    for (int k0 = 0; k0 < 256; k0 += 64) {
        #pragma unroll
        for (int r = 0; r < 4; ++r) {
            int g = r * 256 + t;
            int row = g >> 3, cs = g & 7;
            int colg = cs ^ (row & 7);
            const short* ga = A + (size_t)(posBase + row) * 256 + k0 + colg * 8;
            async_copy16(ga, &As[(r * 256 + wave * 64) * 8]);
            const short* gb = W2p + (size_t)(nb * 128 + row) * 256 + k0 + colg * 8;
            async_copy16(gb, &Bs[(r * 256 + wave * 64) * 8]);
        }
        __syncthreads();
        #pragma unroll
        for (int kc = 0; kc < 2; ++kc) {
            bf16x8 af[4], bfr[4];
            #pragma unroll
            for (int it = 0; it < 4; ++it) {
                int rowa = i0w + it * 16 + ln15;
                int c8a = (kc * 4 + quad) ^ (rowa & 7);
                af[it] = *(const bf16x8*)&As[rowa * 64 + c8a * 8];
                int rowb = n0w + it * 16 + ln15;
                int c8b = (kc * 4 + quad) ^ (rowb & 7);
                bfr[it] = *(const bf16x8*)&Bs[rowb * 64 + c8b * 8];
            }
            #pragma unroll
            for (int it = 0; it < 4; ++it)
                #pragma unroll
                for (int nt = 0; nt < 4; ++nt)
                    acc[it][nt] = __builtin_amdgcn_mfma_f32_16x16x32_bf16(
                        af[it], bfr[nt], acc[it][nt], 0, 0, 0);
        }
        __syncthreads();
    }
    #pragma unroll
    for (int it = 0; it < 4; ++it)
        #pragma unroll
        for (int nt = 0; nt < 4; ++nt)
            #pragma unroll
            for (int r = 0; r < 4; ++r) {
                size_t pos = posBase + i0w + it * 16 + quad * 4 + r;
                int ncol = nb * 128 + n0w + nt * 16 + ln15;
                out[pos * 256 + ncol] = acc[it][nt][r] + fb[ncol];
            }
}

extern "C" void kernel_launch(void* const* d_in, const int* in_sizes, int n_in,
                              void* d_out, int out_size, void* d_ws, size_t ws_size,
                              hipStream_t stream) {
    const float* x1d     = (const float*)d_in[0];
    const float* x2d     = (const float*)d_in[1];
    const float* norm_w  = (const float*)d_in[2];
    const float* norm_b  = (const float*)d_in[3];
    const float* qkv_w   = (const float*)d_in[4];
    const float* x2d_w   = (const float*)d_in[5];
    const float* gate_w  = (const float*)d_in[6];
    const float* gate_b  = (const float*)d_in[7];
    const float* final_w = (const float*)d_in[8];
    const float* final_b = (const float*)d_in[9];
    float* out = (float*)d_out;
    char* w = (char*)d_ws;

    short* Chi   = (short*)(w + OFF_CHI);
    short* Ahi   = (short*)(w + OFF_AHI);
    short* attnB = (short*)(w + OFF_ATTN);
    float* biasT = (float*)(w + OFF_BIAST);
    short* Whi   = (short*)(w + OFF_WHI);
    short* W2p   = (short*)(w + OFF_W2P);
    float* gbp   = (float*)(w + OFF_GBP);

    k_prologue<<<10497, 256, 0, stream>>>(x1d, norm_w, norm_b, qkv_w, gate_w, gate_b,
                                          final_w, x2d, x2d_w, Ahi, Whi, W2p, gbp, biasT);
    k_gemm1m<<<dim3(256, 8), 256, 0, stream>>>(Ahi, Whi, gbp, Chi);
    k_attn3<<<1024, 512, 0, stream>>>(Chi, biasT, attnB);
    k_gemm2m<<<dim3(256, 2), 256, 0, stream>>>(attnB, W2p, final_b, out);
}